// Round 1
// baseline (84.873 us; speedup 1.0000x reference)
//
#include <hip/hip_runtime.h>
#include <math.h>

// Planck*c in J*m (f32 — matches jnp f32 reference math)
#define HCF 1.98644586e-25f

constexpr int BLOCK = 256;
constexpr int RPT   = 4;                 // rays per thread
constexpr int RAYS_PER_BLOCK = BLOCK * RPT;  // 1024

// Main kernel: each block = (ray-group rg) x (theo chunk).
// Stages one 256-entry chunk of unit theo vectors (energy-filtered) in LDS,
// each thread tracks max-dot for RPT rays, then uint-atomicMax into ws.
__global__ __launch_bounds__(BLOCK) void refiner_maxdot_kernel(
    const float* __restrict__ lattice, const float* __restrict__ angle,
    const float* __restrict__ uq_exp,  const int* __restrict__ hkl,
    const float* __restrict__ e_min_p,
    unsigned* __restrict__ maxenc, int n, int m, int nchunks)
{
    __shared__ float4 s_uq[BLOCK];
    const int tid   = threadIdx.x;
    const int chunk = blockIdx.x % nchunks;
    const int rg    = blockIdx.x / nchunks;

    // ---- B_lab = rot(angle) @ inv(prim(lattice))^T, f32, redundant per thread ----
    const float a = lattice[0], b = lattice[1], cc = lattice[2];
    const float cal = cosf(lattice[3]), cbe = cosf(lattice[4]);
    const float cga = cosf(lattice[5]), sga = sinf(lattice[5]);
    const float e3y = (cal - cbe * cga) / sga;
    const float e3z = sqrtf(fmaxf(1.0f - cbe * cbe - e3y * e3y, 1e-12f));
    // prim (upper triangular)
    const float p01 = b * cga, p02 = cc * cbe, p11 = b * sga, p12 = cc * e3y, p22 = cc * e3z;
    // analytic inverse of upper-triangular prim; recip = inv(prim)^T (lower tri)
    const float i00 = 1.0f / a, i11 = 1.0f / p11, i22 = 1.0f / p22;
    const float i01 = -p01 * (i00 * i11);                       // recip[1][0]
    const float i12 = -p12 * (i11 * i22);                       // recip[2][1]
    const float i02 = (p01 * p12 - p02 * p11) * (i00 * i11 * i22); // recip[2][0]
    // rot = Rx(t0) @ Ry(t1) @ Rz(t2)
    const float c0 = cosf(angle[0]), s0 = sinf(angle[0]);
    const float c1 = cosf(angle[1]), s1 = sinf(angle[1]);
    const float c2 = cosf(angle[2]), s2 = sinf(angle[2]);
    const float M00 = c1 * c2,               M01 = -c1 * s2,              M02 = s1;
    const float M10 = c0 * s2 + s0 * s1 * c2, M11 = c0 * c2 - s0 * s1 * s2, M12 = -s0 * c1;
    const float M20 = s0 * s2 - c0 * s1 * c2, M21 = s0 * c2 + c0 * s1 * s2, M22 = c0 * c1;
    // B = M @ recip  (recip rows: [i00,0,0],[i01,i11,0],[i02,i12,i22])
    const float B00 = M00 * i00 + M01 * i01 + M02 * i02;
    const float B01 = M01 * i11 + M02 * i12;
    const float B02 = M02 * i22;
    const float B10 = M10 * i00 + M11 * i01 + M12 * i02;
    const float B11 = M11 * i11 + M12 * i12;
    const float B12 = M12 * i22;
    const float B20 = M20 * i00 + M21 * i01 + M22 * i02;
    const float B21 = M21 * i11 + M22 * i12;
    const float B22 = M22 * i22;

    // ---- stage this chunk's theo unit vectors into LDS (zeros if masked/OOB) ----
    const int ti = chunk * BLOCK + tid;
    float4 v = make_float4(0.f, 0.f, 0.f, 0.f);
    if (ti < m) {
        const float h0 = (float)hkl[3 * ti + 0];
        const float h1 = (float)hkl[3 * ti + 1];
        const float h2 = (float)hkl[3 * ti + 2];
        const float qx = B00 * h0 + B01 * h1 + B02 * h2;
        const float qy = B10 * h0 + B11 * h1 + B12 * h2;
        const float qz = B20 * h0 + B21 * h1 + B22 * h2;
        const float qn = sqrtf(qx * qx + qy * qy + qz * qz);
        const float inv = 1.0f / qn;
        const float ux = qx * inv, uy = qy * inv, uz = qz * inv;
        const float st = fabsf(uz);
        const float energy = HCF * qn / (2.0f * fmaxf(st, 1e-9f));
        if (energy >= e_min_p[0]) v = make_float4(ux, uy, uz, 0.f);
        // masked -> zero vector: dot = 0 -> phi = pi/2 -> exp underflows to exactly
        // 0.0f, same as reference's phi = pi contribution. Bit-identical result.
    }
    s_uq[tid] = v;
    __syncthreads();

    // ---- per-thread rays ----
    float rx[RPT], ry[RPT], rz[RPT], mx[RPT];
    bool valid[RPT];
#pragma unroll
    for (int i = 0; i < RPT; ++i) {
        const int ray = rg * RAYS_PER_BLOCK + i * BLOCK + tid;
        valid[i] = (ray < n);
        float x = 0.f, y = 0.f, z = 0.f;
        if (valid[i]) { x = uq_exp[3 * ray]; y = uq_exp[3 * ray + 1]; z = uq_exp[3 * ray + 2]; }
        rx[i] = x; ry[i] = y; rz[i] = z;
        mx[i] = 0.f;  // clamp-at-zero: negative max-dot contributes exactly 0 anyway
    }

#pragma unroll 4
    for (int j = 0; j < BLOCK; ++j) {
        const float4 t = s_uq[j];   // wave-uniform address -> LDS broadcast, no conflict
#pragma unroll
        for (int i = 0; i < RPT; ++i) {
            const float d = rx[i] * t.x + ry[i] * t.y + rz[i] * t.z;
            mx[i] = fmaxf(mx[i], d);
        }
    }

#pragma unroll
    for (int i = 0; i < RPT; ++i) {
        if (valid[i]) {
            const int ray = rg * RAYS_PER_BLOCK + i * BLOCK + tid;
            // mx >= 0 so float ordering == uint ordering on the bit pattern
            atomicMax(&maxenc[ray], __float_as_uint(mx[i]));
        }
    }
}

// Finalize: phi = acos(clip(max)), w = exp(-0.5 (phi/phi_max)^2), mean via atomics.
__global__ __launch_bounds__(BLOCK) void refiner_finalize_kernel(
    const unsigned* __restrict__ maxenc, const float* __restrict__ phi_max_p,
    float* __restrict__ out, int n)
{
    const int i = blockIdx.x * BLOCK + threadIdx.x;
    float w = 0.f;
    if (i < n) {
        float c = __uint_as_float(maxenc[i]);
        c = fminf(c, 1.0f - 1e-6f);           // reference's upper clip
        const float phi = acosf(c);
        const float t = phi / phi_max_p[0];
        w = expf(-0.5f * t * t);
    }
    // wave (64) reduce
#pragma unroll
    for (int off = 32; off > 0; off >>= 1) w += __shfl_down(w, off, 64);
    __shared__ float s[BLOCK / 64];
    const int lane = threadIdx.x & 63, wv = threadIdx.x >> 6;
    if (lane == 0) s[wv] = w;
    __syncthreads();
    if (threadIdx.x == 0) {
        float tot = 0.f;
#pragma unroll
        for (int k = 0; k < BLOCK / 64; ++k) tot += s[k];
        atomicAdd(out, tot / (float)n);
    }
}

extern "C" void kernel_launch(void* const* d_in, const int* in_sizes, int n_in,
                              void* d_out, int out_size, void* d_ws, size_t ws_size,
                              hipStream_t stream) {
    const float* lattice = (const float*)d_in[0];
    const float* angle   = (const float*)d_in[1];
    const float* uq_exp  = (const float*)d_in[2];
    const int*   hkl     = (const int*)d_in[3];
    const float* phi_max = (const float*)d_in[4];
    const float* e_min   = (const float*)d_in[5];
    const int n = in_sizes[2] / 3;   // ~5000 exp rays
    const int m = in_sizes[3] / 3;   // ~12.7k hkl

    unsigned* maxenc = (unsigned*)d_ws;

    hipMemsetAsync(maxenc, 0, (size_t)n * sizeof(unsigned), stream);
    hipMemsetAsync(d_out, 0, sizeof(float), stream);

    const int nchunks = (m + BLOCK - 1) / BLOCK;
    const int nrg     = (n + RAYS_PER_BLOCK - 1) / RAYS_PER_BLOCK;
    refiner_maxdot_kernel<<<dim3(nrg * nchunks), dim3(BLOCK), 0, stream>>>(
        lattice, angle, uq_exp, hkl, e_min, maxenc, n, m, nchunks);
    refiner_finalize_kernel<<<dim3((n + BLOCK - 1) / BLOCK), dim3(BLOCK), 0, stream>>>(
        maxenc, phi_max, (float*)d_out, n);
}